// Round 2
// baseline (232.780 us; speedup 1.0000x reference)
//
#include <hip/hip_runtime.h>
#include <math.h>

// Problem constants (fixed by the reference's setup_inputs)
#define T_STEPS 16
#define BB      128
#define VOCAB   32000
#define BEAM    4
#define BATCH   (BB / BEAM)   // 32
#define V4      (VOCAB / 4)   // 8000 float4 per row
#define TAU     3.0f          // survivor threshold (8th-largest of 32000 N(0,1) ~ 3.5)
#define CAP     2048          // LDS candidate capacity per row

// ---------------------------------------------------------------------------
// Total-order comparator matching jax.lax.top_k: value descending, index
// ascending on ties. (a > b)?
__device__ __forceinline__ bool gtvi(float av, int ai, float bv, int bi) {
    return (av > bv) || (av == bv && ai < bi);
}

// Insert (x, gi) into a sorted-descending top-8 list held in registers.
__device__ __forceinline__ void ins8(float (&v)[8], int (&ix)[8], float x, int gi) {
    if (gtvi(x, gi, v[7], ix[7])) {
        v[7] = x; ix[7] = gi;
#pragma unroll
        for (int j = 7; j > 0; --j) {
            if (gtvi(v[j], ix[j], v[j - 1], ix[j - 1])) {
                float tv = v[j]; v[j] = v[j - 1]; v[j - 1] = tv;
                int   ti = ix[j]; ix[j] = ix[j - 1]; ix[j - 1] = ti;
            }
        }
    }
}

__device__ __forceinline__ void ins4(float (&v)[4], int (&ix)[4], float x, int gi) {
    if (x > v[3]) {
        v[3] = x; ix[3] = gi;
#pragma unroll
        for (int j = 3; j > 0; --j) {
            if (v[j] > v[j - 1]) {
                float tv = v[j]; v[j] = v[j - 1]; v[j - 1] = tv;
                int   ti = ix[j]; ix[j] = ix[j - 1]; ix[j - 1] = ti;
            }
        }
    }
}

// Wave(64)-level butterfly merge of per-lane sorted-desc 8-lists.
// After this, every lane holds the wave-wide top-8 (lane 0 is authoritative).
__device__ __forceinline__ void wave_merge8(float (&v)[8], int (&ix)[8]) {
#pragma unroll
    for (int m = 1; m < 64; m <<= 1) {
        float u[8]; int ju[8];
#pragma unroll
        for (int k = 0; k < 8; ++k) {
            u[k]  = __shfl_xor(v[k],  m, 64);
            ju[k] = __shfl_xor(ix[k], m, 64);
        }
        // top-8 multiset of two sorted-desc lists: w[k] = max(v[k], u[7-k])
        float w[8]; int jw[8];
#pragma unroll
        for (int k = 0; k < 8; ++k) {
            if (gtvi(u[7 - k], ju[7 - k], v[k], ix[k])) { w[k] = u[7 - k]; jw[k] = ju[7 - k]; }
            else                                        { w[k] = v[k];     jw[k] = ix[k];     }
        }
        // w is bitonic -> bitonic merge to sorted descending (dist 4,2,1)
#define CE_DESC(a, b)                                                         \
        if (gtvi(w[b], jw[b], w[a], jw[a])) {                                 \
            float tv = w[a]; w[a] = w[b]; w[b] = tv;                          \
            int   ti = jw[a]; jw[a] = jw[b]; jw[b] = ti;                      \
        }
        CE_DESC(0, 4) CE_DESC(1, 5) CE_DESC(2, 6) CE_DESC(3, 7)
        CE_DESC(0, 2) CE_DESC(1, 3) CE_DESC(4, 6) CE_DESC(5, 7)
        CE_DESC(0, 1) CE_DESC(2, 3) CE_DESC(4, 5) CE_DESC(6, 7)
#undef CE_DESC
#pragma unroll
        for (int k = 0; k < 8; ++k) { v[k] = w[k]; ix[k] = jw[k]; }
    }
}

// ---------------------------------------------------------------------------
// Phase 1: per (step,row): sum(exp(x)) + exact top-8 of x excluding pad/unk.
// Fast path: threshold-filter survivors (x > TAU) into LDS (expected ~43 of
// 32000), then wave 0 does exact top-8 of survivors. Falls back to a full
// exact scan if the survivor count is <8 or >CAP (never for N(0,1) rows).
__global__ __launch_bounds__(256) void phase1_topk_lsm(
    const float* __restrict__ logits,
    const int*   __restrict__ pad_p,
    const int*   __restrict__ unk_p,
    float* __restrict__ topv,
    int*   __restrict__ topi)
{
    __shared__ float s_cv[CAP];
    __shared__ int   s_ci[CAP];
    __shared__ float s_red[4];
    __shared__ float s_logS;
    __shared__ int   s_cnt;

    const int row = blockIdx.x;            // t*BB + r
    const int tid = threadIdx.x;
    const int pad = *pad_p, unk = *unk_p;
    const float4* __restrict__ src =
        reinterpret_cast<const float4*>(logits + (size_t)row * VOCAB);

    if (tid == 0) s_cnt = 0;
    __syncthreads();

    // ---- hot loop: exp-sum + threshold compaction (memory-bound) ----
    float tsum = 0.0f;
    for (int kv = tid; kv < V4; kv += 256) {
        float4 q = src[kv];
        const int gi = kv * 4;
        tsum += (__expf(q.x) + __expf(q.y)) + (__expf(q.z) + __expf(q.w));
        if (q.x > TAU && (gi + 0) != pad && (gi + 0) != unk) {
            int p = atomicAdd(&s_cnt, 1); if (p < CAP) { s_cv[p] = q.x; s_ci[p] = gi + 0; }
        }
        if (q.y > TAU && (gi + 1) != pad && (gi + 1) != unk) {
            int p = atomicAdd(&s_cnt, 1); if (p < CAP) { s_cv[p] = q.y; s_ci[p] = gi + 1; }
        }
        if (q.z > TAU && (gi + 2) != pad && (gi + 2) != unk) {
            int p = atomicAdd(&s_cnt, 1); if (p < CAP) { s_cv[p] = q.z; s_ci[p] = gi + 2; }
        }
        if (q.w > TAU && (gi + 3) != pad && (gi + 3) != unk) {
            int p = atomicAdd(&s_cnt, 1); if (p < CAP) { s_cv[p] = q.w; s_ci[p] = gi + 3; }
        }
    }

    // ---- exp-sum reduction: wave butterfly, then cross-wave via LDS ----
#pragma unroll
    for (int m = 1; m < 64; m <<= 1) tsum += __shfl_xor(tsum, m, 64);
    const int wv = tid >> 6, ln = tid & 63;
    if (ln == 0) s_red[wv] = tsum;
    __syncthreads();
    if (tid == 0) s_logS = logf((s_red[0] + s_red[1]) + (s_red[2] + s_red[3]));
    __syncthreads();

    const float logS = s_logS;
    const int   cnt  = s_cnt;
    float* ov = topv + (size_t)row * 8;
    int*   oi = topi + (size_t)row * 8;

    if (cnt >= 8 && cnt <= CAP) {
        // ---- fast path: exact top-8 of LDS survivors (wave 0 only) ----
        if (tid < 64) {
            float v[8]; int ix[8];
#pragma unroll
            for (int k = 0; k < 8; ++k) { v[k] = -INFINITY; ix[k] = 0x7FFFFFFF; }
            for (int c = tid; c < cnt; c += 64) ins8(v, ix, s_cv[c], s_ci[c]);
            wave_merge8(v, ix);
            if (tid == 0) {
#pragma unroll
                for (int k = 0; k < 8; ++k) { ov[k] = v[k] - logS; oi[k] = ix[k]; }
            }
        }
    } else {
        // ---- exact fallback: full-row scan with per-thread top-8 ----
        float v[8]; int ix[8];
#pragma unroll
        for (int k = 0; k < 8; ++k) { v[k] = -INFINITY; ix[k] = 0x7FFFFFFF; }
        for (int kv = tid; kv < V4; kv += 256) {
            float4 q = src[kv];
            const int gi = kv * 4;
            if ((gi + 0) != pad && (gi + 0) != unk) ins8(v, ix, q.x, gi + 0);
            if ((gi + 1) != pad && (gi + 1) != unk) ins8(v, ix, q.y, gi + 1);
            if ((gi + 2) != pad && (gi + 2) != unk) ins8(v, ix, q.z, gi + 2);
            if ((gi + 3) != pad && (gi + 3) != unk) ins8(v, ix, q.w, gi + 3);
        }
        wave_merge8(v, ix);
        if (ln == 0) {
#pragma unroll
            for (int k = 0; k < 8; ++k) { s_cv[wv * 8 + k] = v[k]; s_ci[wv * 8 + k] = ix[k]; }
        }
        __syncthreads();
        if (tid == 0) {
            float bv[8]; int bi[8];
#pragma unroll
            for (int k = 0; k < 8; ++k) { bv[k] = -INFINITY; bi[k] = 0x7FFFFFFF; }
            for (int j = 0; j < 32; ++j) ins8(bv, bi, s_cv[j], s_ci[j]);
#pragma unroll
            for (int k = 0; k < 8; ++k) { ov[k] = bv[k] - logS; oi[k] = bi[k]; }
        }
    }
}

// ---------------------------------------------------------------------------
// Phase 2: sequential 16-step beam scan per batch (32 independent blocks).
// Per step: 32 candidates (4 beams x their top-8) -> top-8 -> eos mask ->
// top-4. Records backpointers; backtrace reconstructs token sequences.
__global__ __launch_bounds__(64) void phase2_beam_scan(
    const float* __restrict__ topv,
    const int*   __restrict__ topi,
    const int*   __restrict__ eos_p,
    float* __restrict__ out)
{
    const int b   = blockIdx.x;   // batch index
    const int tid = threadIdx.x;
    const int eos = *eos_p;

    __shared__ float cv[32];
    __shared__ int   cw[32];
    __shared__ float sc[BEAM];
    __shared__ int   rb[T_STEPS][BEAM];
    __shared__ int   rw[T_STEPS][BEAM];

    if (tid < BEAM) sc[tid] = 0.0f;
    __syncthreads();

    for (int t = 0; t < T_STEPS; ++t) {
        if (tid < 32) {
            const int beam = tid >> 3;
            const int row  = t * BB + b * BEAM + beam;
            cv[tid] = topv[(size_t)row * 8 + (tid & 7)] + sc[beam];
            cw[tid] = topi[(size_t)row * 8 + (tid & 7)];
        }
        __syncthreads();
        if (tid == 0) {
            // top-8 of the 32 candidates (value desc, lower index on ties)
            float tv[8]; int tj[8];
#pragma unroll
            for (int k = 0; k < 8; ++k) { tv[k] = -INFINITY; tj[k] = 0x7FFFFFFF; }
            for (int j = 0; j < 32; ++j) ins8(tv, tj, cv[j], j);
            // eos mask + top-4 of the 8
            float s4[4]; int p4[4];
#pragma unroll
            for (int k = 0; k < 4; ++k) { s4[k] = -INFINITY; p4[k] = 0; }
#pragma unroll
            for (int k = 0; k < 8; ++k) {
                float val = tv[k];
                if (cw[tj[k]] == eos) val = -INFINITY;
                ins4(s4, p4, val, k);
            }
#pragma unroll
            for (int j = 0; j < 4; ++j) {
                const int cidx = tj[p4[j]];
                rb[t][j] = cidx >> 3;      // source (old) beam
                rw[t][j] = cw[cidx];       // chosen word
                sc[j]    = s4[j];          // new cumulative scores
            }
        }
        __syncthreads();
    }

    // Backtrace + output (written as float32 values; d_out = [scores|tokens])
    if (tid < BEAM) {
        out[b * BEAM + tid] = sc[tid];
        float* tout = out + BATCH * BEAM + (size_t)(b * BEAM + tid) * (T_STEPS + 1);
        int bp = tid;
#pragma unroll
        for (int t = T_STEPS - 1; t >= 0; --t) {
            tout[t + 1] = (float)rw[t][bp];
            bp = rb[t][bp];
        }
        tout[0] = (float)eos;   // begin token (init value, never overwritten)
    }
}

// ---------------------------------------------------------------------------
extern "C" void kernel_launch(void* const* d_in, const int* in_sizes, int n_in,
                              void* d_out, int out_size, void* d_ws, size_t ws_size,
                              hipStream_t stream) {
    const float* logits = (const float*)d_in[0];
    const int*   pad_p  = (const int*)d_in[1];
    const int*   unk_p  = (const int*)d_in[2];
    const int*   eos_p  = (const int*)d_in[3];
    // d_in[4] = beam_size (hardcoded 4 to match shapes)

    // Workspace: topv [T*BB*8] f32, then topi [T*BB*8] i32  (128 KB total)
    float* topv = (float*)d_ws;
    int*   topi = (int*)(topv + T_STEPS * BB * 8);

    hipLaunchKernelGGL(phase1_topk_lsm, dim3(T_STEPS * BB), dim3(256), 0, stream,
                       logits, pad_p, unk_p, topv, topi);
    hipLaunchKernelGGL(phase2_beam_scan, dim3(BATCH), dim3(64), 0, stream,
                       topv, topi, eos_p, (float*)d_out);
}

// Round 3
// 142.555 us; speedup vs baseline: 1.6329x; 1.6329x over previous
//
#include <hip/hip_runtime.h>
#include <math.h>

// Problem constants (fixed by the reference's setup_inputs)
#define T_STEPS 16
#define BB      128
#define VOCAB   32000
#define BEAM    4
#define BATCH   (BB / BEAM)   // 32
#define V4      (VOCAB / 4)   // 8000 float4 per row
#define TAU     2.75f         // survivor threshold: E[cnt]=96, 8th-largest ~3.5
#define CAP     2048          // LDS candidate capacity per row

// ---------------------------------------------------------------------------
// Total-order comparator matching jax.lax.top_k: value descending, index
// ascending on ties. (a ranks before b)?
__device__ __forceinline__ bool gtvi(float av, int ai, float bv, int bi) {
    return (av > bv) || (av == bv && ai < bi);
}

// Insert (x, gi) into a sorted-descending top-8 list held in registers.
__device__ __forceinline__ void ins8(float (&v)[8], int (&ix)[8], float x, int gi) {
    if (gtvi(x, gi, v[7], ix[7])) {
        v[7] = x; ix[7] = gi;
#pragma unroll
        for (int j = 7; j > 0; --j) {
            if (gtvi(v[j], ix[j], v[j - 1], ix[j - 1])) {
                float tv = v[j]; v[j] = v[j - 1]; v[j - 1] = tv;
                int   ti = ix[j]; ix[j] = ix[j - 1]; ix[j - 1] = ti;
            }
        }
    }
}

// Wave(64)-level butterfly merge of per-lane sorted-desc 8-lists.
// After this, every lane holds the wave-wide top-8.
__device__ __forceinline__ void wave_merge8(float (&v)[8], int (&ix)[8]) {
#pragma unroll
    for (int m = 1; m < 64; m <<= 1) {
        float u[8]; int ju[8];
#pragma unroll
        for (int k = 0; k < 8; ++k) {
            u[k]  = __shfl_xor(v[k],  m, 64);
            ju[k] = __shfl_xor(ix[k], m, 64);
        }
        float w[8]; int jw[8];
#pragma unroll
        for (int k = 0; k < 8; ++k) {
            if (gtvi(u[7 - k], ju[7 - k], v[k], ix[k])) { w[k] = u[7 - k]; jw[k] = ju[7 - k]; }
            else                                        { w[k] = v[k];     jw[k] = ix[k];     }
        }
#define CE_DESC(a, b)                                                         \
        if (gtvi(w[b], jw[b], w[a], jw[a])) {                                 \
            float tv = w[a]; w[a] = w[b]; w[b] = tv;                          \
            int   ti = jw[a]; jw[a] = jw[b]; jw[b] = ti;                      \
        }
        CE_DESC(0, 4) CE_DESC(1, 5) CE_DESC(2, 6) CE_DESC(3, 7)
        CE_DESC(0, 2) CE_DESC(1, 3) CE_DESC(4, 6) CE_DESC(5, 7)
        CE_DESC(0, 1) CE_DESC(2, 3) CE_DESC(4, 5) CE_DESC(6, 7)
#undef CE_DESC
#pragma unroll
        for (int k = 0; k < 8; ++k) { v[k] = w[k]; ix[k] = jw[k]; }
    }
}

// ---------------------------------------------------------------------------
// Phase 1: per (step,row): sum(exp(x)) + exact top-8 of x excluding pad/unk.
// Hot loop is pure streaming: exp-sum + one fmax-guarded rare branch.
// pad/unk filtering happens at selection time (denominator includes them,
// matching log_softmax-then-mask in the reference).
__global__ __launch_bounds__(256) void phase1_topk_lsm(
    const float* __restrict__ logits,
    const int*   __restrict__ pad_p,
    const int*   __restrict__ unk_p,
    float* __restrict__ topv,
    int*   __restrict__ topi)
{
    __shared__ float s_cv[CAP];
    __shared__ int   s_ci[CAP];
    __shared__ float s_red[4];
    __shared__ float s_logS;
    __shared__ int   s_cnt;

    const int row = blockIdx.x;            // t*BB + r
    const int tid = threadIdx.x;
    const int pad = *pad_p, unk = *unk_p;
    const float4* __restrict__ src =
        reinterpret_cast<const float4*>(logits + (size_t)row * VOCAB);

    if (tid == 0) s_cnt = 0;
    __syncthreads();

    // ---- hot loop: exp-sum + threshold compaction (memory-bound) ----
    float tsum = 0.0f;
    for (int kv = tid; kv < V4; kv += 256) {
        float4 q = src[kv];
        tsum += (__expf(q.x) + __expf(q.y)) + (__expf(q.z) + __expf(q.w));
        float m = fmaxf(fmaxf(q.x, q.y), fmaxf(q.z, q.w));
        if (m > TAU) {                                   // rare (~29%/wave-iter)
            const int gi = kv * 4;
            if (q.x > TAU) { int p = atomicAdd(&s_cnt, 1); if (p < CAP) { s_cv[p] = q.x; s_ci[p] = gi + 0; } }
            if (q.y > TAU) { int p = atomicAdd(&s_cnt, 1); if (p < CAP) { s_cv[p] = q.y; s_ci[p] = gi + 1; } }
            if (q.z > TAU) { int p = atomicAdd(&s_cnt, 1); if (p < CAP) { s_cv[p] = q.z; s_ci[p] = gi + 2; } }
            if (q.w > TAU) { int p = atomicAdd(&s_cnt, 1); if (p < CAP) { s_cv[p] = q.w; s_ci[p] = gi + 3; } }
        }
    }

    // ---- exp-sum reduction: wave butterfly, then cross-wave via LDS ----
#pragma unroll
    for (int m = 1; m < 64; m <<= 1) tsum += __shfl_xor(tsum, m, 64);
    const int wv = tid >> 6, ln = tid & 63;
    if (ln == 0) s_red[wv] = tsum;
    __syncthreads();
    if (tid == 0) s_logS = logf((s_red[0] + s_red[1]) + (s_red[2] + s_red[3]));
    __syncthreads();

    const float logS = s_logS;
    const int   cnt  = s_cnt;
    float* ov = topv + (size_t)row * 8;
    int*   oi = topi + (size_t)row * 8;

    if (cnt >= 10 && cnt <= CAP) {
        // ---- fast path: exact top-8 of LDS survivors (wave 0 only) ----
        // cnt>=10 guarantees >=8 valid survivors even if pad & unk both passed.
        if (tid < 64) {
            float v[8]; int ix[8];
#pragma unroll
            for (int k = 0; k < 8; ++k) { v[k] = -INFINITY; ix[k] = 0x7FFFFFFF; }
            for (int c = tid; c < cnt; c += 64) {
                const int w = s_ci[c];
                if (w != pad && w != unk) ins8(v, ix, s_cv[c], w);
            }
            wave_merge8(v, ix);
            if (tid == 0) {
#pragma unroll
                for (int k = 0; k < 8; ++k) { ov[k] = v[k] - logS; oi[k] = ix[k]; }
            }
        }
    } else {
        // ---- exact fallback: full-row scan with per-thread top-8 ----
        float v[8]; int ix[8];
#pragma unroll
        for (int k = 0; k < 8; ++k) { v[k] = -INFINITY; ix[k] = 0x7FFFFFFF; }
        for (int kv = tid; kv < V4; kv += 256) {
            float4 q = src[kv];
            const int gi = kv * 4;
            if ((gi + 0) != pad && (gi + 0) != unk) ins8(v, ix, q.x, gi + 0);
            if ((gi + 1) != pad && (gi + 1) != unk) ins8(v, ix, q.y, gi + 1);
            if ((gi + 2) != pad && (gi + 2) != unk) ins8(v, ix, q.z, gi + 2);
            if ((gi + 3) != pad && (gi + 3) != unk) ins8(v, ix, q.w, gi + 3);
        }
        wave_merge8(v, ix);
        if (ln == 0) {
#pragma unroll
            for (int k = 0; k < 8; ++k) { s_cv[wv * 8 + k] = v[k]; s_ci[wv * 8 + k] = ix[k]; }
        }
        __syncthreads();
        if (tid == 0) {
            float bv[8]; int bi[8];
#pragma unroll
            for (int k = 0; k < 8; ++k) { bv[k] = -INFINITY; bi[k] = 0x7FFFFFFF; }
            for (int j = 0; j < 32; ++j) ins8(bv, bi, s_cv[j], s_ci[j]);
#pragma unroll
            for (int k = 0; k < 8; ++k) { ov[k] = bv[k] - logS; oi[k] = bi[k]; }
        }
    }
}

// ---------------------------------------------------------------------------
// Phase 2: sequential 16-step beam scan, one wave per batch, fully
// wave-parallel. All candidates preloaded to LDS once; per step a 64-lane
// bitonic sort by (val desc, cand-idx asc) gives the exact top-8, then an
// 8-lane mini-sort after eos masking gives the exact top_k(masked, 4).
__global__ __launch_bounds__(64) void phase2_beam_scan(
    const float* __restrict__ topv,
    const int*   __restrict__ topi,
    const int*   __restrict__ eos_p,
    float* __restrict__ out)
{
    const int b    = blockIdx.x;   // batch index
    const int lane = threadIdx.x;  // 0..63, single wave
    const int eos  = *eos_p;

    __shared__ float s_v[T_STEPS][32];
    __shared__ int   s_w[T_STEPS][32];
    __shared__ float s_sc[BEAM];
    __shared__ int   s_rb[T_STEPS][BEAM];
    __shared__ int   s_rw[T_STEPS][BEAM];

    // Preload all 16*32 candidate (val, word) pairs for this batch.
    // Row layout: row = t*BB + b*BEAM + beam; beams consecutive -> for fixed
    // (t,b) the 32 pairs are contiguous at (t*BB + b*BEAM)*8.
    for (int g = lane; g < T_STEPS * 32; g += 64) {
        const int t = g >> 5, j = g & 31;
        const size_t off = (size_t)t * (BB * 8) + (size_t)b * (BEAM * 8) + j;
        s_v[t][j] = topv[off];
        s_w[t][j] = topi[off];
    }
    if (lane < BEAM) s_sc[lane] = 0.0f;
    __syncthreads();

    for (int t = 0; t < T_STEPS; ++t) {
        // Candidate per lane; lanes 32..63 are -inf padding that loses ties.
        float val; int word, cj;
        if (lane < 32) {
            cj   = lane;                       // beam*8 + pos
            word = s_w[t][lane];
            val  = s_v[t][lane] + s_sc[lane >> 3];
        } else {
            cj = 64 + lane; word = 0; val = -INFINITY;
        }

        // ---- 64-lane bitonic sort, descending by (val, cj asc) ----
#pragma unroll
        for (int k = 2; k <= 64; k <<= 1) {
#pragma unroll
            for (int j = k >> 1; j > 0; j >>= 1) {
                const float ov = __shfl_xor(val,  j, 64);
                const int   oc = __shfl_xor(cj,   j, 64);
                const int   ow = __shfl_xor(word, j, 64);
                const bool dirDesc   = ((lane & k) == 0);   // k=64: always true
                const bool iAmLow    = ((lane & j) == 0);
                const bool mineFirst = gtvi(val, cj, ov, oc);
                const bool takeOther = dirDesc ? (iAmLow ? !mineFirst : mineFirst)
                                               : (iAmLow ? mineFirst : !mineFirst);
                if (takeOther) { val = ov; cj = oc; word = ow; }
            }
        }

        // ---- lanes 0..7 = top-8 desc. eos mask, then exact top_k(masked,4)
        //      via an 8-lane bitonic sort by (masked desc, position asc). ----
        float mval; int pos = lane, srcb = 0, w8 = 0;
        if (lane < 8) {
            w8   = word;
            srcb = cj >> 3;
            const bool iseos = (w8 == eos) && (val > -INFINITY);
            mval = iseos ? -INFINITY : val;
        } else {
            mval = -INFINITY;
        }
#pragma unroll
        for (int k = 2; k <= 8; k <<= 1) {
#pragma unroll
            for (int j = k >> 1; j > 0; j >>= 1) {
                const float ov = __shfl_xor(mval, j, 64);
                const int   op = __shfl_xor(pos,  j, 64);
                const int   ob = __shfl_xor(srcb, j, 64);
                const int   ow = __shfl_xor(w8,   j, 64);
                const bool dirDesc   = ((lane & k) == 0);
                const bool iAmLow    = ((lane & j) == 0);
                const bool mineFirst = gtvi(mval, pos, ov, op);
                const bool takeOther = dirDesc ? (iAmLow ? !mineFirst : mineFirst)
                                               : (iAmLow ? mineFirst : !mineFirst);
                if (takeOther) { mval = ov; pos = op; srcb = ob; w8 = ow; }
            }
        }

        if (lane < 4) {
            s_sc[lane]    = mval;   // new cumulative scores (sel_scores)
            s_rb[t][lane] = srcb;   // source (old) beam
            s_rw[t][lane] = w8;     // chosen word
        }
        __syncthreads();
    }

    // Backtrace + output (d_out = [scores (128) | tokens (128*17)], f32)
    if (lane < BEAM) {
        out[b * BEAM + lane] = s_sc[lane];
        float* tout = out + BATCH * BEAM + (size_t)(b * BEAM + lane) * (T_STEPS + 1);
        int bp = lane;
#pragma unroll
        for (int t = T_STEPS - 1; t >= 0; --t) {
            tout[t + 1] = (float)s_rw[t][bp];
            bp = s_rb[t][bp];
        }
        tout[0] = (float)eos;   // begin token
    }
}

// ---------------------------------------------------------------------------
extern "C" void kernel_launch(void* const* d_in, const int* in_sizes, int n_in,
                              void* d_out, int out_size, void* d_ws, size_t ws_size,
                              hipStream_t stream) {
    const float* logits = (const float*)d_in[0];
    const int*   pad_p  = (const int*)d_in[1];
    const int*   unk_p  = (const int*)d_in[2];
    const int*   eos_p  = (const int*)d_in[3];
    // d_in[4] = beam_size (hardcoded 4 to match shapes)

    // Workspace: topv [T*BB*8] f32, then topi [T*BB*8] i32  (128 KB total)
    float* topv = (float*)d_ws;
    int*   topi = (int*)(topv + T_STEPS * BB * 8);

    hipLaunchKernelGGL(phase1_topk_lsm, dim3(T_STEPS * BB), dim3(256), 0, stream,
                       logits, pad_p, unk_p, topv, topi);
    hipLaunchKernelGGL(phase2_beam_scan, dim3(BATCH), dim3(64), 0, stream,
                       topv, topi, eos_p, (float*)d_out);
}

// Round 4
// 109.499 us; speedup vs baseline: 2.1259x; 1.3019x over previous
//
#include <hip/hip_runtime.h>
#include <math.h>

// Problem constants (fixed by the reference's setup_inputs)
#define T_STEPS 16
#define BB      128
#define VOCAB   32000
#define BEAM    4
#define BATCH   (BB / BEAM)   // 32
#define V4      (VOCAB / 4)   // 8000 float4 per row
#define TAU     2.75f         // survivor threshold: E[survivors]=~96 for N(0,1)

// ---------------------------------------------------------------------------
// Total-order comparator matching jax.lax.top_k: value descending, index
// ascending on ties. (a ranks before b)?
__device__ __forceinline__ bool gtvi(float av, int ai, float bv, int bi) {
    return (av > bv) || (av == bv && ai < bi);
}

// Insert (x, gi) into a sorted-descending top-8 list held in registers.
__device__ __forceinline__ void ins8(float (&v)[8], int (&ix)[8], float x, int gi) {
    if (gtvi(x, gi, v[7], ix[7])) {
        v[7] = x; ix[7] = gi;
#pragma unroll
        for (int j = 7; j > 0; --j) {
            if (gtvi(v[j], ix[j], v[j - 1], ix[j - 1])) {
                float tv = v[j]; v[j] = v[j - 1]; v[j - 1] = tv;
                int   ti = ix[j]; ix[j] = ix[j - 1]; ix[j - 1] = ti;
            }
        }
    }
}

// Wave(64)-level butterfly merge of per-lane sorted-desc 8-lists.
// After this, every lane holds the wave-wide top-8.
__device__ __forceinline__ void wave_merge8(float (&v)[8], int (&ix)[8]) {
#pragma unroll
    for (int m = 1; m < 64; m <<= 1) {
        float u[8]; int ju[8];
#pragma unroll
        for (int k = 0; k < 8; ++k) {
            u[k]  = __shfl_xor(v[k],  m, 64);
            ju[k] = __shfl_xor(ix[k], m, 64);
        }
        float w[8]; int jw[8];
#pragma unroll
        for (int k = 0; k < 8; ++k) {
            if (gtvi(u[7 - k], ju[7 - k], v[k], ix[k])) { w[k] = u[7 - k]; jw[k] = ju[7 - k]; }
            else                                        { w[k] = v[k];     jw[k] = ix[k];     }
        }
#define CE_DESC(a, b)                                                         \
        if (gtvi(w[b], jw[b], w[a], jw[a])) {                                 \
            float tv = w[a]; w[a] = w[b]; w[b] = tv;                          \
            int   ti = jw[a]; jw[a] = jw[b]; jw[b] = ti;                      \
        }
        CE_DESC(0, 4) CE_DESC(1, 5) CE_DESC(2, 6) CE_DESC(3, 7)
        CE_DESC(0, 2) CE_DESC(1, 3) CE_DESC(4, 6) CE_DESC(5, 7)
        CE_DESC(0, 1) CE_DESC(2, 3) CE_DESC(4, 5) CE_DESC(6, 7)
#undef CE_DESC
#pragma unroll
        for (int k = 0; k < 8; ++k) { v[k] = w[k]; ix[k] = jw[k]; }
    }
}

// ---------------------------------------------------------------------------
// Phase 1: per (step,row): sum(exp(x)) + exact top-8 of x excluding pad/unk.
// Hot loop: ZERO LDS traffic. Register top-8 guarded by threshold (rarely
// executes), software-pipelined float4 loads (2 in flight per thread).
// Survivor count is block-reduced once; <8 triggers an exact rescan.
__global__ __launch_bounds__(256) void phase1_topk_lsm(
    const float* __restrict__ logits,
    const int*   __restrict__ pad_p,
    const int*   __restrict__ unk_p,
    float* __restrict__ topv,
    int*   __restrict__ topi)
{
    __shared__ float s_red[4];
    __shared__ int   s_icnt[4];
    __shared__ float s_mv[32];
    __shared__ int   s_mi[32];
    __shared__ float s_logS;
    __shared__ int   s_tot;

    const int row = blockIdx.x;            // t*BB + r
    const int tid = threadIdx.x;
    const int pad = *pad_p, unk = *unk_p;
    const float4* __restrict__ src =
        reinterpret_cast<const float4*>(logits + (size_t)row * VOCAB);

    float v[8]; int ix[8];
#pragma unroll
    for (int k = 0; k < 8; ++k) { v[k] = -INFINITY; ix[k] = 0x7FFFFFFF; }
    float tsum = 0.0f;
    int   scnt = 0;

    auto process = [&](float4 q, int gi) {
        tsum += (__expf(q.x) + __expf(q.y)) + (__expf(q.z) + __expf(q.w));
        const float mx = fmaxf(fmaxf(q.x, q.y), fmaxf(q.z, q.w));
        if (mx > TAU) {                    // taken on ~54% of wave-iters
            if (q.x > TAU) { if ((gi + 0) != pad && (gi + 0) != unk) { ins8(v, ix, q.x, gi + 0); ++scnt; } }
            if (q.y > TAU) { if ((gi + 1) != pad && (gi + 1) != unk) { ins8(v, ix, q.y, gi + 1); ++scnt; } }
            if (q.z > TAU) { if ((gi + 2) != pad && (gi + 2) != unk) { ins8(v, ix, q.z, gi + 2); ++scnt; } }
            if (q.w > TAU) { if ((gi + 3) != pad && (gi + 3) != unk) { ins8(v, ix, q.w, gi + 3); ++scnt; } }
        }
    };

    // ---- software-pipelined hot loop: 31 full iters + 64-thread tail ----
    // kvs covered: tid + i*256 for i=0..30 (max 7935), then 7936+tid (tid<64).
    float4 q = src[tid];
    int kv = tid;
    for (int i = 0; i < 30; ++i) {
        float4 qn = src[kv + 256];         // prefetch next (2 loads in flight)
        process(q, kv * 4);
        q = qn; kv += 256;
    }
    process(q, kv * 4);
    if (tid < 64) {
        float4 qt = src[7936 + tid];
        process(qt, (7936 + tid) * 4);
    }

    // ---- block reductions: exp-sum and survivor count ----
#pragma unroll
    for (int m = 1; m < 64; m <<= 1) {
        tsum += __shfl_xor(tsum, m, 64);
        scnt += __shfl_xor(scnt, m, 64);
    }
    const int wv = tid >> 6, ln = tid & 63;
    if (ln == 0) { s_red[wv] = tsum; s_icnt[wv] = scnt; }
    __syncthreads();
    if (tid == 0) {
        s_logS = logf((s_red[0] + s_red[1]) + (s_red[2] + s_red[3]));
        s_tot  = (s_icnt[0] + s_icnt[1]) + (s_icnt[2] + s_icnt[3]);
    }
    __syncthreads();
    const float logS = s_logS;

    if (s_tot < 8) {
        // ---- exact fallback (never taken for N(0,1) rows): full rescan ----
#pragma unroll
        for (int k = 0; k < 8; ++k) { v[k] = -INFINITY; ix[k] = 0x7FFFFFFF; }
        for (int k2 = tid; k2 < V4; k2 += 256) {
            float4 f = src[k2];
            const int gi = k2 * 4;
            if ((gi + 0) != pad && (gi + 0) != unk) ins8(v, ix, f.x, gi + 0);
            if ((gi + 1) != pad && (gi + 1) != unk) ins8(v, ix, f.y, gi + 1);
            if ((gi + 2) != pad && (gi + 2) != unk) ins8(v, ix, f.z, gi + 2);
            if ((gi + 3) != pad && (gi + 3) != unk) ins8(v, ix, f.w, gi + 3);
        }
    }

    // ---- merge: wave butterfly, then cross-wave via LDS ----
    wave_merge8(v, ix);
    if (ln == 0) {
#pragma unroll
        for (int k = 0; k < 8; ++k) { s_mv[wv * 8 + k] = v[k]; s_mi[wv * 8 + k] = ix[k]; }
    }
    __syncthreads();
    if (tid == 0) {
        float bv[8]; int bi[8];
#pragma unroll
        for (int k = 0; k < 8; ++k) { bv[k] = -INFINITY; bi[k] = 0x7FFFFFFF; }
        for (int j = 0; j < 32; ++j) ins8(bv, bi, s_mv[j], s_mi[j]);
        float* ov = topv + (size_t)row * 8;
        int*   oi = topi + (size_t)row * 8;
#pragma unroll
        for (int k = 0; k < 8; ++k) { ov[k] = bv[k] - logS; oi[k] = bi[k]; }
    }
}

// ---------------------------------------------------------------------------
// Phase 2: sequential 16-step beam scan, one wave per batch, fully
// wave-parallel. All candidates preloaded to LDS once; per step a 64-lane
// bitonic sort by (val desc, cand-idx asc) gives the exact top-8, then an
// 8-lane mini-sort after eos masking gives the exact top_k(masked, 4).
__global__ __launch_bounds__(64) void phase2_beam_scan(
    const float* __restrict__ topv,
    const int*   __restrict__ topi,
    const int*   __restrict__ eos_p,
    float* __restrict__ out)
{
    const int b    = blockIdx.x;   // batch index
    const int lane = threadIdx.x;  // 0..63, single wave
    const int eos  = *eos_p;

    __shared__ float s_v[T_STEPS][32];
    __shared__ int   s_w[T_STEPS][32];
    __shared__ float s_sc[BEAM];
    __shared__ int   s_rb[T_STEPS][BEAM];
    __shared__ int   s_rw[T_STEPS][BEAM];

    for (int g = lane; g < T_STEPS * 32; g += 64) {
        const int t = g >> 5, j = g & 31;
        const size_t off = (size_t)t * (BB * 8) + (size_t)b * (BEAM * 8) + j;
        s_v[t][j] = topv[off];
        s_w[t][j] = topi[off];
    }
    if (lane < BEAM) s_sc[lane] = 0.0f;
    __syncthreads();

    for (int t = 0; t < T_STEPS; ++t) {
        float val; int word, cj;
        if (lane < 32) {
            cj   = lane;                       // beam*8 + pos
            word = s_w[t][lane];
            val  = s_v[t][lane] + s_sc[lane >> 3];
        } else {
            cj = 64 + lane; word = 0; val = -INFINITY;
        }

        // ---- 64-lane bitonic sort, descending by (val, cj asc) ----
#pragma unroll
        for (int k = 2; k <= 64; k <<= 1) {
#pragma unroll
            for (int j = k >> 1; j > 0; j >>= 1) {
                const float ov = __shfl_xor(val,  j, 64);
                const int   oc = __shfl_xor(cj,   j, 64);
                const int   ow = __shfl_xor(word, j, 64);
                const bool dirDesc   = ((lane & k) == 0);
                const bool iAmLow    = ((lane & j) == 0);
                const bool mineFirst = gtvi(val, cj, ov, oc);
                const bool takeOther = dirDesc ? (iAmLow ? !mineFirst : mineFirst)
                                               : (iAmLow ? mineFirst : !mineFirst);
                if (takeOther) { val = ov; cj = oc; word = ow; }
            }
        }

        // ---- lanes 0..7 = top-8 desc. eos mask, then exact top_k(masked,4)
        float mval; int pos = lane, srcb = 0, w8 = 0;
        if (lane < 8) {
            w8   = word;
            srcb = cj >> 3;
            const bool iseos = (w8 == eos) && (val > -INFINITY);
            mval = iseos ? -INFINITY : val;
        } else {
            mval = -INFINITY;
        }
#pragma unroll
        for (int k = 2; k <= 8; k <<= 1) {
#pragma unroll
            for (int j = k >> 1; j > 0; j >>= 1) {
                const float ov = __shfl_xor(mval, j, 64);
                const int   op = __shfl_xor(pos,  j, 64);
                const int   ob = __shfl_xor(srcb, j, 64);
                const int   ow = __shfl_xor(w8,   j, 64);
                const bool dirDesc   = ((lane & k) == 0);
                const bool iAmLow    = ((lane & j) == 0);
                const bool mineFirst = gtvi(mval, pos, ov, op);
                const bool takeOther = dirDesc ? (iAmLow ? !mineFirst : mineFirst)
                                               : (iAmLow ? mineFirst : !mineFirst);
                if (takeOther) { mval = ov; pos = op; srcb = ob; w8 = ow; }
            }
        }

        if (lane < 4) {
            s_sc[lane]    = mval;   // new cumulative scores (sel_scores)
            s_rb[t][lane] = srcb;   // source (old) beam
            s_rw[t][lane] = w8;     // chosen word
        }
        __syncthreads();
    }

    // Backtrace + output (d_out = [scores (128) | tokens (128*17)], f32)
    if (lane < BEAM) {
        out[b * BEAM + lane] = s_sc[lane];
        float* tout = out + BATCH * BEAM + (size_t)(b * BEAM + lane) * (T_STEPS + 1);
        int bp = lane;
#pragma unroll
        for (int t = T_STEPS - 1; t >= 0; --t) {
            tout[t + 1] = (float)s_rw[t][bp];
            bp = s_rb[t][bp];
        }
        tout[0] = (float)eos;   // begin token
    }
}

// ---------------------------------------------------------------------------
extern "C" void kernel_launch(void* const* d_in, const int* in_sizes, int n_in,
                              void* d_out, int out_size, void* d_ws, size_t ws_size,
                              hipStream_t stream) {
    const float* logits = (const float*)d_in[0];
    const int*   pad_p  = (const int*)d_in[1];
    const int*   unk_p  = (const int*)d_in[2];
    const int*   eos_p  = (const int*)d_in[3];
    // d_in[4] = beam_size (hardcoded 4 to match shapes)

    // Workspace: topv [T*BB*8] f32, then topi [T*BB*8] i32  (128 KB total)
    float* topv = (float*)d_ws;
    int*   topi = (int*)(topv + T_STEPS * BB * 8);

    hipLaunchKernelGGL(phase1_topk_lsm, dim3(T_STEPS * BB), dim3(256), 0, stream,
                       logits, pad_p, unk_p, topv, topi);
    hipLaunchKernelGGL(phase2_beam_scan, dim3(BATCH), dim3(64), 0, stream,
                       topv, topi, eos_p, (float*)d_out);
}